// Round 4
// baseline (111.005 us; speedup 1.0000x reference)
//
#include <hip/hip_runtime.h>

#define MTOT 8192
#define NTOT 8192
#define DD   64

typedef __bf16 bf16x8 __attribute__((ext_vector_type(8)));
typedef float  f32x16 __attribute__((ext_vector_type(16)));
typedef unsigned short u16;
typedef unsigned short u16x4 __attribute__((ext_vector_type(4)));
typedef unsigned short u16x8 __attribute__((ext_vector_type(8)));

// Round-to-nearest-even fp32 -> bf16 (top 16 bits), bit-trick.
__device__ __forceinline__ u16 bf16_rne(float v) {
    unsigned int u = __float_as_uint(v);
    u = u + 0x7FFFu + ((u >> 16) & 1u);
    return (u16)(u >> 16);
}
__device__ __forceinline__ float bf16_to_f32(u16 h) {
    return __uint_as_float(((unsigned int)h) << 16);
}

#define MFMA(a, b, c) __builtin_amdgcn_mfma_f32_32x32x16_bf16((a), (b), (c), 0, 0, 0)

// ================= pre-pass: fp32 -> bf16 hi/lo + row norms =================
// 4 threads per row, 2 matrices. 65536 threads total.
__global__ __launch_bounds__(256)
void rbf_pre_kernel(const float* __restrict__ X, const float* __restrict__ Y,
                    u16* __restrict__ Xhi, u16* __restrict__ Xlo,
                    u16* __restrict__ Yhi, u16* __restrict__ Ylo,
                    float* __restrict__ xqs, float* __restrict__ yqs)
{
    const int gid = blockIdx.x * 256 + threadIdx.x;
    const int mat = gid >> 15;            // 0 = X, 1 = Y
    const int r4  = gid & 32767;
    const int row = r4 >> 2;
    const int q   = r4 & 3;
    const float* src = mat ? Y : X;
    u16* hi  = mat ? Yhi : Xhi;
    u16* lo  = mat ? Ylo : Xlo;
    float* nrm = mat ? yqs : xqs;

    const long base = (long)row * DD + q * 16;
    float s = 0.f;
    u16x8 h0, h1, l0, l1;
    #pragma unroll
    for (int c = 0; c < 4; ++c) {
        const float4 v = *reinterpret_cast<const float4*>(src + base + c * 4);
        const float vv[4] = {v.x, v.y, v.z, v.w};
        #pragma unroll
        for (int e = 0; e < 4; ++e) {
            const int idx = c * 4 + e;
            const float x = vv[e];
            s = fmaf(x, x, s);
            const u16 hh = bf16_rne(x);
            const u16 ll = bf16_rne(x - bf16_to_f32(hh));
            if (idx < 8) { h0[idx] = hh; l0[idx] = ll; }
            else         { h1[idx - 8] = hh; l1[idx - 8] = ll; }
        }
    }
    // reduce the row norm across the 4 threads handling this row
    s += __shfl_xor(s, 1);
    s += __shfl_xor(s, 2);
    if (q == 0) nrm[row] = s;

    *reinterpret_cast<u16x8*>(hi + base)     = h0;
    *reinterpret_cast<u16x8*>(hi + base + 8) = h1;
    *reinterpret_cast<u16x8*>(lo + base)     = l0;
    *reinterpret_cast<u16x8*>(lo + base + 8) = l1;
}

// ================= main: LDS-free, barrier-free MFMA + NT stores =================
// 256 threads = 4 waves; wave w owns cols [w*32, w*32+32), rows 0..127 of the tile.
// Fragment (lane l): row = base + (l&31), k = ks*16 + (l>>5)*8 + 0..7 -> 16B load.
// C/D (verified): row = (r&3) + 8*(r>>2) + 4*(l>>5), col = l&31 (X passed first).
__global__ __launch_bounds__(256, 4)
void rbf_main_kernel(const u16* __restrict__ Xhi, const u16* __restrict__ Xlo,
                     const u16* __restrict__ Yhi, const u16* __restrict__ Ylo,
                     const float* __restrict__ xqs, const float* __restrict__ yqs,
                     const float* __restrict__ gamma_p,
                     float* __restrict__ out)
{
    const int t = threadIdx.x;
    const int w = t >> 6;          // n-tile 0..3
    const int l = t & 63;
    const int lr = l & 31;
    const int lk = (l >> 5) * 8;   // k sub-offset
    const long row0 = (long)blockIdx.y * 128;
    const long col0 = (long)blockIdx.x * 128;

    f32x16 acc[4];
    #pragma unroll
    for (int mt = 0; mt < 4; ++mt)
        #pragma unroll
        for (int r = 0; r < 16; ++r) acc[mt][r] = 0.f;

    const long arow0 = (row0 + lr) * DD + lk;           // + mt*32*DD + ks*16
    const long brow  = (col0 + w * 32 + lr) * DD + lk;  // + ks*16

    #pragma unroll
    for (int ks = 0; ks < 4; ++ks) {
        const bf16x8 bh = *reinterpret_cast<const bf16x8*>(Yhi + brow + ks * 16);
        const bf16x8 bl = *reinterpret_cast<const bf16x8*>(Ylo + brow + ks * 16);
        #pragma unroll
        for (int mt = 0; mt < 4; ++mt) {
            const long ao = arow0 + mt * (32 * DD) + ks * 16;
            const bf16x8 ah = *reinterpret_cast<const bf16x8*>(Xhi + ao);
            const bf16x8 al = *reinterpret_cast<const bf16x8*>(Xlo + ao);
            acc[mt] = MFMA(ah, bh, acc[mt]);
            acc[mt] = MFMA(ah, bl, acc[mt]);
            acc[mt] = MFMA(al, bh, acc[mt]);
        }
    }

    // epilogue: arg = -g*(xq + yq - 2*dot), clamped <= 0; out = exp(arg)
    const float g  = gamma_p[0];
    const float g2 = 2.0f * g;
    const long ncol = col0 + w * 32 + lr;
    const float cy = -g * yqs[ncol];
    const int rsub = 4 * (l >> 5);
    float* const ocol = out + ncol;

    #pragma unroll
    for (int mt = 0; mt < 4; ++mt) {
        #pragma unroll
        for (int q = 0; q < 4; ++q) {
            const long rbase = row0 + mt * 32 + 8 * q + rsub;
            const float4 xv = *reinterpret_cast<const float4*>(xqs + rbase);
            const float xa[4] = {xv.x, xv.y, xv.z, xv.w};
            #pragma unroll
            for (int j = 0; j < 4; ++j) {
                float arg = fmaf(g2, acc[mt][q * 4 + j], fmaf(-g, xa[j], cy));
                arg = fminf(arg, 0.f);
                __builtin_nontemporal_store(__expf(arg), ocol + (rbase + j) * (long)NTOT);
            }
        }
    }
}

// ================= fallback (R2 kernel, known-good) if ws too small =================
__global__ __launch_bounds__(256, 2)
void rbf_fallback_kernel(const float* __restrict__ X,
                         const float* __restrict__ Y,
                         const float* __restrict__ gamma_p,
                         float* __restrict__ out)
{
    __shared__ unsigned short XfH[4][4][64][8];
    __shared__ unsigned short XfL[4][4][64][8];
    __shared__ unsigned short YfH[4][4][64][8];
    __shared__ unsigned short YfL[4][4][64][8];
    __shared__ float xq[128];
    __shared__ float yq[128];

    const int t = threadIdx.x;
    const long row0 = (long)blockIdx.y * 128;
    const long col0 = (long)blockIdx.x * 128;

    {
        const int k0   = (t & 15) * 4;
        const int ks   = k0 >> 4;
        const int l32  = ((k0 >> 3) & 1) << 5;
        const int slot = k0 & 4;
        #pragma unroll
        for (int i = 0; i < 8; ++i) {
            const int row  = (t >> 4) + i * 16;
            const int mt   = row >> 5;
            const int lane = (row & 31) | l32;
            const float4 vx = *reinterpret_cast<const float4*>(X + (row0 + row) * DD + k0);
            const float4 vy = *reinterpret_cast<const float4*>(Y + (col0 + row) * DD + k0);
            float xv[4] = {vx.x, vx.y, vx.z, vx.w};
            float yv[4] = {vy.x, vy.y, vy.z, vy.w};
            u16x4 xh, xl, yh, yl;
            #pragma unroll
            for (int e = 0; e < 4; ++e) {
                const u16 hx = bf16_rne(xv[e]);
                xh[e] = hx; xl[e] = bf16_rne(xv[e] - bf16_to_f32(hx));
                const u16 hy = bf16_rne(yv[e]);
                yh[e] = hy; yl[e] = bf16_rne(yv[e] - bf16_to_f32(hy));
            }
            *reinterpret_cast<u16x4*>(&XfH[mt][ks][lane][slot]) = xh;
            *reinterpret_cast<u16x4*>(&XfL[mt][ks][lane][slot]) = xl;
            *reinterpret_cast<u16x4*>(&YfH[mt][ks][lane][slot]) = yh;
            *reinterpret_cast<u16x4*>(&YfL[mt][ks][lane][slot]) = yl;
        }
    }
    {
        const int r = t & 127;
        const float* p = (t < 128) ? (X + (row0 + r) * DD) : (Y + (col0 + r) * DD);
        float s0 = 0.f, s1 = 0.f, s2 = 0.f, s3 = 0.f;
        #pragma unroll
        for (int c = 0; c < 16; ++c) {
            const float4 v = reinterpret_cast<const float4*>(p)[c];
            s0 = fmaf(v.x, v.x, s0); s1 = fmaf(v.y, v.y, s1);
            s2 = fmaf(v.z, v.z, s2); s3 = fmaf(v.w, v.w, s3);
        }
        const float s = (s0 + s1) + (s2 + s3);
        if (t < 128) xq[r] = s; else yq[r] = s;
    }
    __syncthreads();

    const int w = t >> 6;
    const int l = t & 63;
    const int mt0 = (w >> 1) * 2;
    const int nt0 = (w & 1) * 2;

    bf16x8 aH[2][4], aL[2][4];
    #pragma unroll
    for (int i = 0; i < 2; ++i)
        #pragma unroll
        for (int ks = 0; ks < 4; ++ks) {
            aH[i][ks] = *reinterpret_cast<const bf16x8*>(&XfH[mt0 + i][ks][l][0]);
            aL[i][ks] = *reinterpret_cast<const bf16x8*>(&XfL[mt0 + i][ks][l][0]);
        }

    f32x16 acc[2][2];
    #pragma unroll
    for (int i = 0; i < 2; ++i)
        #pragma unroll
        for (int j = 0; j < 2; ++j)
            #pragma unroll
            for (int r = 0; r < 16; ++r) acc[i][j][r] = 0.f;

    #pragma unroll
    for (int ks = 0; ks < 4; ++ks) {
        const bf16x8 b0h = *reinterpret_cast<const bf16x8*>(&YfH[nt0 + 0][ks][l][0]);
        const bf16x8 b1h = *reinterpret_cast<const bf16x8*>(&YfH[nt0 + 1][ks][l][0]);
        const bf16x8 b0l = *reinterpret_cast<const bf16x8*>(&YfL[nt0 + 0][ks][l][0]);
        const bf16x8 b1l = *reinterpret_cast<const bf16x8*>(&YfL[nt0 + 1][ks][l][0]);
        acc[0][0] = MFMA(aH[0][ks], b0h, acc[0][0]);
        acc[0][1] = MFMA(aH[0][ks], b1h, acc[0][1]);
        acc[1][0] = MFMA(aH[1][ks], b0h, acc[1][0]);
        acc[1][1] = MFMA(aH[1][ks], b1h, acc[1][1]);
        acc[0][0] = MFMA(aH[0][ks], b0l, acc[0][0]);
        acc[0][1] = MFMA(aH[0][ks], b1l, acc[0][1]);
        acc[1][0] = MFMA(aH[1][ks], b0l, acc[1][0]);
        acc[1][1] = MFMA(aH[1][ks], b1l, acc[1][1]);
        acc[0][0] = MFMA(aL[0][ks], b0h, acc[0][0]);
        acc[0][1] = MFMA(aL[0][ks], b1h, acc[0][1]);
        acc[1][0] = MFMA(aL[1][ks], b0h, acc[1][0]);
        acc[1][1] = MFMA(aL[1][ks], b1h, acc[1][1]);
    }

    const float g = gamma_p[0];
    const int l5x4 = (l >> 5) * 4;
    const int ln = l & 31;
    #pragma unroll
    for (int i = 0; i < 2; ++i) {
        const int mt = mt0 + i;
        float xv[16];
        #pragma unroll
        for (int r = 0; r < 16; ++r)
            xv[r] = xq[mt * 32 + (r & 3) + 8 * (r >> 2) + l5x4];
        #pragma unroll
        for (int j = 0; j < 2; ++j) {
            const int nt = nt0 + j;
            const float yv = yq[nt * 32 + ln];
            const long gr = row0 + mt * 32;
            const long gc = col0 + nt * 32 + ln;
            #pragma unroll
            for (int r = 0; r < 16; ++r) {
                float s = fmaf(-2.f, acc[i][j][r], xv[r] + yv);
                s = fmaxf(s, 0.f);
                const long rr = gr + (r & 3) + 8 * (r >> 2) + l5x4;
                out[rr * NTOT + gc] = __expf(-g * s);
            }
        }
    }
}

extern "C" void kernel_launch(void* const* d_in, const int* in_sizes, int n_in,
                              void* d_out, int out_size, void* d_ws, size_t ws_size,
                              hipStream_t stream) {
    (void)in_sizes; (void)n_in; (void)out_size;
    const float* X = (const float*)d_in[0];
    const float* Y = (const float*)d_in[1];
    const float* gamma_p = (const float*)d_in[2];
    float* out = (float*)d_out;

    const size_t SPLIT = (size_t)MTOT * DD;  // 524288 elements per hi/lo array
    const size_t need = 4 * SPLIT * sizeof(u16) + (MTOT + NTOT) * sizeof(float);

    dim3 grid(NTOT / 128, MTOT / 128);  // (64, 64)

    if (ws_size >= need) {
        u16* Xhi = (u16*)d_ws;
        u16* Xlo = Xhi + SPLIT;
        u16* Yhi = Xlo + SPLIT;
        u16* Ylo = Yhi + SPLIT;
        float* xqs = (float*)(Ylo + SPLIT);
        float* yqs = xqs + MTOT;
        rbf_pre_kernel<<<256, 256, 0, stream>>>(X, Y, Xhi, Xlo, Yhi, Ylo, xqs, yqs);
        rbf_main_kernel<<<grid, 256, 0, stream>>>(Xhi, Xlo, Yhi, Ylo, xqs, yqs, gamma_p, out);
    } else {
        rbf_fallback_kernel<<<grid, 256, 0, stream>>>(X, Y, gamma_p, out);
    }
}

// Round 5
// 56.135 us; speedup vs baseline: 1.9775x; 1.9775x over previous
//
#include <hip/hip_runtime.h>

#define MTOT 8192
#define NTOT 8192
#define DD   64
#define SPLIT (MTOT * DD)   // 524288 elems per hi/lo array

typedef __bf16 bf16x8 __attribute__((ext_vector_type(8)));
typedef float  f32x16 __attribute__((ext_vector_type(16)));
typedef unsigned short u16;
typedef unsigned short u16x4 __attribute__((ext_vector_type(4)));
typedef unsigned short u16x8 __attribute__((ext_vector_type(8)));

// Round-to-nearest-even fp32 -> bf16 (top 16 bits), bit-trick.
__device__ __forceinline__ u16 bf16_rne(float v) {
    unsigned int u = __float_as_uint(v);
    u = u + 0x7FFFu + ((u >> 16) & 1u);
    return (u16)(u >> 16);
}
__device__ __forceinline__ float bf16_to_f32(u16 h) {
    return __uint_as_float(((unsigned int)h) << 16);
}

#define MFMA(a, b, c) __builtin_amdgcn_mfma_f32_32x32x16_bf16((a), (b), (c), 0, 0, 0)

// ============ pre-pass: fp32 -> hi/lo bf16 in FRAGMENT-LINEAR order + norms ============
// Fragment order (matches R2's proven LDS layout, now global):
//   elem(row,k) -> [(tt*4 + ks)*64 + lane]*8 + slot
//   tt = row>>5, ks = k>>4, lane = (row&31) | (((k>>3)&1)<<5), slot = k&7.
// Thread: one (row, ks) pair -> 16 consecutive k. 4 threads/row for the norm shuffle.
__global__ __launch_bounds__(256)
void rbf_pre_kernel(const float* __restrict__ X, const float* __restrict__ Y,
                    u16* __restrict__ XhiF, u16* __restrict__ XloF,
                    u16* __restrict__ YhiF, u16* __restrict__ YloF,
                    float* __restrict__ xqs, float* __restrict__ yqs)
{
    const int gid = blockIdx.x * 256 + threadIdx.x;
    const int mat = gid >> 15;            // 0 = X, 1 = Y
    const int r4  = gid & 32767;
    const int row = r4 >> 2;
    const int q   = r4 & 3;               // == ks
    const float* src = mat ? Y : X;
    u16* hi  = mat ? YhiF : XhiF;
    u16* lo  = mat ? YloF : XloF;
    float* nrm = mat ? yqs : xqs;

    const long rbase = (long)row * DD + q * 16;
    float s = 0.f;
    u16x8 h0, h1, l0, l1;
    #pragma unroll
    for (int c = 0; c < 4; ++c) {
        const float4 v = *reinterpret_cast<const float4*>(src + rbase + c * 4);
        const float vv[4] = {v.x, v.y, v.z, v.w};
        #pragma unroll
        for (int e = 0; e < 4; ++e) {
            const int idx = c * 4 + e;
            const float x = vv[e];
            s = fmaf(x, x, s);
            const u16 hh = bf16_rne(x);
            const u16 ll = bf16_rne(x - bf16_to_f32(hh));
            if (idx < 8) { h0[idx] = hh; l0[idx] = ll; }
            else         { h1[idx - 8] = hh; l1[idx - 8] = ll; }
        }
    }
    s += __shfl_xor(s, 1);
    s += __shfl_xor(s, 2);
    if (q == 0) nrm[row] = s;

    const int tt = row >> 5, lr = row & 31;
    const long fbase = (long)(tt * 4 + q) * 512;   // (tile,ks) subtile of 512 u16
    *reinterpret_cast<u16x8*>(hi + fbase + lr * 8)        = h0;
    *reinterpret_cast<u16x8*>(hi + fbase + (32 + lr) * 8) = h1;
    *reinterpret_cast<u16x8*>(lo + fbase + lr * 8)        = l0;
    *reinterpret_cast<u16x8*>(lo + fbase + (32 + lr) * 8) = l1;
}

// ============ main: memcpy-stage fragments -> LDS, MFMA, NT stores ============
// 256 threads = 4 waves, 128x128 tile, 64 KB LDS, 2 blocks/CU.
__global__ __launch_bounds__(256, 2)
void rbf_main_kernel(const u16* __restrict__ XhiF, const u16* __restrict__ XloF,
                     const u16* __restrict__ YhiF, const u16* __restrict__ YloF,
                     const float* __restrict__ xqs, const float* __restrict__ yqs,
                     const float* __restrict__ gamma_p,
                     float* __restrict__ out)
{
    __shared__ __align__(16) u16 S[4][8192];   // Xhi | Xlo | Yhi | Ylo panel (16 KB each)

    const int t = threadIdx.x;
    const int w = t >> 6;
    const int l = t & 63;

    // bijective XCD swizzle: 4096 blocks, 8 XCDs, 512 contiguous tiles per XCD
    const int bid = blockIdx.x;
    const int swz = ((bid & 7) << 9) | (bid >> 3);
    const int bm = swz >> 6;
    const int bn = swz & 63;
    const long row0 = (long)bm * 128;
    const long col0 = (long)bn * 128;

    // ---- stage: wave w copies its 16 KB panel (pure memcpy, no conversion) ----
    const u16* gsrc;
    if      (w == 0) gsrc = XhiF + (long)bm * 8192;
    else if (w == 1) gsrc = XloF + (long)bm * 8192;
    else if (w == 2) gsrc = YhiF + (long)bn * 8192;
    else             gsrc = YloF + (long)bn * 8192;
    u16* const ldst = &S[w][0];
    #pragma unroll
    for (int c = 0; c < 16; ++c) {
        const int off = c * 512 + l * 8;   // lane-linear 16B chunks, conflict-free
        *reinterpret_cast<int4*>(ldst + off) = *reinterpret_cast<const int4*>(gsrc + off);
    }
    __syncthreads();

    // ---- per-wave 64x64 quadrant: 2x2 tiles of 32x32, split-bf16 hh+hl+lh ----
    const int mt0 = (w >> 1) * 2;
    const int nt0 = (w & 1) * 2;

    bf16x8 aH[2][4], aL[2][4];
    #pragma unroll
    for (int i = 0; i < 2; ++i)
        #pragma unroll
        for (int ks = 0; ks < 4; ++ks) {
            aH[i][ks] = *reinterpret_cast<const bf16x8*>(&S[0][((mt0 + i) * 4 + ks) * 512 + l * 8]);
            aL[i][ks] = *reinterpret_cast<const bf16x8*>(&S[1][((mt0 + i) * 4 + ks) * 512 + l * 8]);
        }

    f32x16 acc[2][2];
    #pragma unroll
    for (int i = 0; i < 2; ++i)
        #pragma unroll
        for (int j = 0; j < 2; ++j)
            #pragma unroll
            for (int r = 0; r < 16; ++r) acc[i][j][r] = 0.f;

    #pragma unroll
    for (int ks = 0; ks < 4; ++ks) {
        const bf16x8 b0h = *reinterpret_cast<const bf16x8*>(&S[2][((nt0 + 0) * 4 + ks) * 512 + l * 8]);
        const bf16x8 b1h = *reinterpret_cast<const bf16x8*>(&S[2][((nt0 + 1) * 4 + ks) * 512 + l * 8]);
        const bf16x8 b0l = *reinterpret_cast<const bf16x8*>(&S[3][((nt0 + 0) * 4 + ks) * 512 + l * 8]);
        const bf16x8 b1l = *reinterpret_cast<const bf16x8*>(&S[3][((nt0 + 1) * 4 + ks) * 512 + l * 8]);
        acc[0][0] = MFMA(aH[0][ks], b0h, acc[0][0]);
        acc[0][1] = MFMA(aH[0][ks], b1h, acc[0][1]);
        acc[1][0] = MFMA(aH[1][ks], b0h, acc[1][0]);
        acc[1][1] = MFMA(aH[1][ks], b1h, acc[1][1]);
        acc[0][0] = MFMA(aH[0][ks], b0l, acc[0][0]);
        acc[0][1] = MFMA(aH[0][ks], b1l, acc[0][1]);
        acc[1][0] = MFMA(aH[1][ks], b0l, acc[1][0]);
        acc[1][1] = MFMA(aH[1][ks], b1l, acc[1][1]);
        acc[0][0] = MFMA(aL[0][ks], b0h, acc[0][0]);
        acc[0][1] = MFMA(aL[0][ks], b1h, acc[0][1]);
        acc[1][0] = MFMA(aL[1][ks], b0h, acc[1][0]);
        acc[1][1] = MFMA(aL[1][ks], b1h, acc[1][1]);
    }

    // ---- epilogue: arg = -g*(xq+yq-2*dot) clamped <=0; NT store exp(arg) ----
    // C/D (verified): row = (r&3)+8*(r>>2)+4*(l>>5), col = l&31.
    const float g  = gamma_p[0];
    const float g2 = 2.0f * g;
    const int l5x4 = (l >> 5) * 4;
    const int ln   = l & 31;

    #pragma unroll
    for (int i = 0; i < 2; ++i) {
        const int mt = mt0 + i;
        float xv[16];
        #pragma unroll
        for (int p = 0; p < 4; ++p) {
            const float4 x4 = *reinterpret_cast<const float4*>(xqs + row0 + mt * 32 + 8 * p + l5x4);
            xv[p * 4 + 0] = x4.x; xv[p * 4 + 1] = x4.y;
            xv[p * 4 + 2] = x4.z; xv[p * 4 + 3] = x4.w;
        }
        #pragma unroll
        for (int j = 0; j < 2; ++j) {
            const int nt = nt0 + j;
            const long gc = col0 + nt * 32 + ln;
            const float cy = -g * yqs[gc];
            float* const obase = out + gc;
            #pragma unroll
            for (int r = 0; r < 16; ++r) {
                float arg = fmaf(g2, acc[i][j][r], fmaf(-g, xv[r], cy));
                arg = fminf(arg, 0.f);
                const long rr = row0 + mt * 32 + (r & 3) + 8 * (r >> 2) + l5x4;
                __builtin_nontemporal_store(__expf(arg), obase + rr * (long)NTOT);
            }
        }
    }
}

// ============ fallback (R2 kernel, known-good 80.7us) if ws too small ============
__global__ __launch_bounds__(256, 2)
void rbf_fallback_kernel(const float* __restrict__ X,
                         const float* __restrict__ Y,
                         const float* __restrict__ gamma_p,
                         float* __restrict__ out)
{
    __shared__ unsigned short XfH[4][4][64][8];
    __shared__ unsigned short XfL[4][4][64][8];
    __shared__ unsigned short YfH[4][4][64][8];
    __shared__ unsigned short YfL[4][4][64][8];
    __shared__ float xq[128];
    __shared__ float yq[128];

    const int t = threadIdx.x;
    const long row0 = (long)blockIdx.y * 128;
    const long col0 = (long)blockIdx.x * 128;

    {
        const int k0   = (t & 15) * 4;
        const int ks   = k0 >> 4;
        const int l32  = ((k0 >> 3) & 1) << 5;
        const int slot = k0 & 4;
        #pragma unroll
        for (int i = 0; i < 8; ++i) {
            const int row  = (t >> 4) + i * 16;
            const int mt   = row >> 5;
            const int lane = (row & 31) | l32;
            const float4 vx = *reinterpret_cast<const float4*>(X + (row0 + row) * DD + k0);
            const float4 vy = *reinterpret_cast<const float4*>(Y + (col0 + row) * DD + k0);
            float xv[4] = {vx.x, vx.y, vx.z, vx.w};
            float yv[4] = {vy.x, vy.y, vy.z, vy.w};
            u16x4 xh, xl, yh, yl;
            #pragma unroll
            for (int e = 0; e < 4; ++e) {
                const u16 hx = bf16_rne(xv[e]);
                xh[e] = hx; xl[e] = bf16_rne(xv[e] - bf16_to_f32(hx));
                const u16 hy = bf16_rne(yv[e]);
                yh[e] = hy; yl[e] = bf16_rne(yv[e] - bf16_to_f32(hy));
            }
            *reinterpret_cast<u16x4*>(&XfH[mt][ks][lane][slot]) = xh;
            *reinterpret_cast<u16x4*>(&XfL[mt][ks][lane][slot]) = xl;
            *reinterpret_cast<u16x4*>(&YfH[mt][ks][lane][slot]) = yh;
            *reinterpret_cast<u16x4*>(&YfL[mt][ks][lane][slot]) = yl;
        }
    }
    {
        const int r = t & 127;
        const float* p = (t < 128) ? (X + (row0 + r) * DD) : (Y + (col0 + r) * DD);
        float s0 = 0.f, s1 = 0.f, s2 = 0.f, s3 = 0.f;
        #pragma unroll
        for (int c = 0; c < 16; ++c) {
            const float4 v = reinterpret_cast<const float4*>(p)[c];
            s0 = fmaf(v.x, v.x, s0); s1 = fmaf(v.y, v.y, s1);
            s2 = fmaf(v.z, v.z, s2); s3 = fmaf(v.w, v.w, s3);
        }
        const float s = (s0 + s1) + (s2 + s3);
        if (t < 128) xq[r] = s; else yq[r] = s;
    }
    __syncthreads();

    const int w = t >> 6;
    const int l = t & 63;
    const int mt0 = (w >> 1) * 2;
    const int nt0 = (w & 1) * 2;

    bf16x8 aH[2][4], aL[2][4];
    #pragma unroll
    for (int i = 0; i < 2; ++i)
        #pragma unroll
        for (int ks = 0; ks < 4; ++ks) {
            aH[i][ks] = *reinterpret_cast<const bf16x8*>(&XfH[mt0 + i][ks][l][0]);
            aL[i][ks] = *reinterpret_cast<const bf16x8*>(&XfL[mt0 + i][ks][l][0]);
        }

    f32x16 acc[2][2];
    #pragma unroll
    for (int i = 0; i < 2; ++i)
        #pragma unroll
        for (int j = 0; j < 2; ++j)
            #pragma unroll
            for (int r = 0; r < 16; ++r) acc[i][j][r] = 0.f;

    #pragma unroll
    for (int ks = 0; ks < 4; ++ks) {
        const bf16x8 b0h = *reinterpret_cast<const bf16x8*>(&YfH[nt0 + 0][ks][l][0]);
        const bf16x8 b1h = *reinterpret_cast<const bf16x8*>(&YfH[nt0 + 1][ks][l][0]);
        const bf16x8 b0l = *reinterpret_cast<const bf16x8*>(&YfL[nt0 + 0][ks][l][0]);
        const bf16x8 b1l = *reinterpret_cast<const bf16x8*>(&YfL[nt0 + 1][ks][l][0]);
        acc[0][0] = MFMA(aH[0][ks], b0h, acc[0][0]);
        acc[0][1] = MFMA(aH[0][ks], b1h, acc[0][1]);
        acc[1][0] = MFMA(aH[1][ks], b0h, acc[1][0]);
        acc[1][1] = MFMA(aH[1][ks], b1h, acc[1][1]);
        acc[0][0] = MFMA(aH[0][ks], b0l, acc[0][0]);
        acc[0][1] = MFMA(aH[0][ks], b1l, acc[0][1]);
        acc[1][0] = MFMA(aH[1][ks], b0l, acc[1][0]);
        acc[1][1] = MFMA(aH[1][ks], b1l, acc[1][1]);
        acc[0][0] = MFMA(aL[0][ks], b0h, acc[0][0]);
        acc[0][1] = MFMA(aL[0][ks], b1h, acc[0][1]);
        acc[1][0] = MFMA(aL[1][ks], b0h, acc[1][0]);
        acc[1][1] = MFMA(aL[1][ks], b1h, acc[1][1]);
    }

    const float g = gamma_p[0];
    const int l5x4 = (l >> 5) * 4;
    const int ln = l & 31;
    #pragma unroll
    for (int i = 0; i < 2; ++i) {
        const int mt = mt0 + i;
        float xv[16];
        #pragma unroll
        for (int r = 0; r < 16; ++r)
            xv[r] = xq[mt * 32 + (r & 3) + 8 * (r >> 2) + l5x4];
        #pragma unroll
        for (int j = 0; j < 2; ++j) {
            const int nt = nt0 + j;
            const float yv = yq[nt * 32 + ln];
            const long gr = row0 + mt * 32;
            const long gc = col0 + nt * 32 + ln;
            #pragma unroll
            for (int r = 0; r < 16; ++r) {
                float s = fmaf(-2.f, acc[i][j][r], xv[r] + yv);
                s = fmaxf(s, 0.f);
                const long rr = gr + (r & 3) + 8 * (r >> 2) + l5x4;
                out[rr * NTOT + gc] = __expf(-g * s);
            }
        }
    }
}

extern "C" void kernel_launch(void* const* d_in, const int* in_sizes, int n_in,
                              void* d_out, int out_size, void* d_ws, size_t ws_size,
                              hipStream_t stream) {
    (void)in_sizes; (void)n_in; (void)out_size;
    const float* X = (const float*)d_in[0];
    const float* Y = (const float*)d_in[1];
    const float* gamma_p = (const float*)d_in[2];
    float* out = (float*)d_out;

    const size_t need = 4 * (size_t)SPLIT * sizeof(u16) + (MTOT + NTOT) * sizeof(float);

    if (ws_size >= need) {
        u16* XhiF = (u16*)d_ws;
        u16* XloF = XhiF + SPLIT;
        u16* YhiF = XloF + SPLIT;
        u16* YloF = YhiF + SPLIT;
        float* xqs = (float*)(YloF + SPLIT);
        float* yqs = xqs + MTOT;
        rbf_pre_kernel<<<256, 256, 0, stream>>>(X, Y, XhiF, XloF, YhiF, YloF, xqs, yqs);
        rbf_main_kernel<<<4096, 256, 0, stream>>>(XhiF, XloF, YhiF, YloF, xqs, yqs, gamma_p, out);
    } else {
        dim3 grid(NTOT / 128, MTOT / 128);
        rbf_fallback_kernel<<<grid, 256, 0, stream>>>(X, Y, gamma_p, out);
    }
}